// Round 7
// baseline (704.642 us; speedup 1.0000x reference)
//
#include <hip/hip_runtime.h>
#include <hip/hip_bf16.h>
#include <math.h>

#define B_DIM 65536
#define N_DIM 1024
#define DT_C 0.01f
#define NS_SCALE 0.01f   // NOISE_STD * sqrt(DT) = 0.1 * 0.1

typedef __attribute__((ext_vector_type(8))) short bf16x8;
typedef __attribute__((ext_vector_type(4))) float f32x4;

__device__ __forceinline__ unsigned short f2bf(float f) {
    union { float f; unsigned int u; } a;
    a.f = f;
    unsigned int r = a.u + 0x7fffu + ((a.u >> 16) & 1u);
    return (unsigned short)(r >> 16);
}
__device__ __forceinline__ float bf2f(unsigned short u) {
    union { unsigned int u; float f; } a;
    a.u = ((unsigned int)u) << 16;
    return a.f;
}
__device__ __forceinline__ void gload_lds16(const void* g, void* l) {
    __builtin_amdgcn_global_load_lds(
        (const __attribute__((address_space(1))) void*)g,
        (__attribute__((address_space(3))) void*)l, 16, 0, 0);
}

// K (fp32, row-major N x N) -> bf16
__global__ void k_convK(const float* __restrict__ K, unsigned short* __restrict__ Kbf) {
    int i = blockIdx.x * blockDim.x + threadIdx.x;
    float4 v = reinterpret_cast<const float4*>(K)[i];
    ushort4 o;
    o.x = f2bf(v.x); o.y = f2bf(v.y); o.z = f2bf(v.z); o.w = f2bf(v.w);
    reinterpret_cast<ushort4*>(Kbf)[i] = o;
}

// Precompute sin/cos(theta) for rows [rbase, rbase+R) into sc (bf16).
// Group g=row/64 occupies sc rows [g*128, g*128+128): 64 sin rows, 64 cos rows.
__global__ __launch_bounds__(256)
void k_prep(const float* __restrict__ theta, unsigned short* __restrict__ sc, int rbase) {
    const int i   = blockIdx.x * 256 + threadIdx.x;
    const int row = i >> 7;
    const int kk  = (i & 127) * 8;
    const float* tp = theta + (size_t)(rbase + row) * N_DIM + kk;
    float4 a = *reinterpret_cast<const float4*>(tp);
    float4 b = *reinterpret_cast<const float4*>(tp + 4);
    float in[8] = {a.x, a.y, a.z, a.w, b.x, b.y, b.z, b.w};
    bf16x8 sv, cv;
#pragma unroll
    for (int e = 0; e < 8; ++e) {
        float s, c;
        __sincosf(in[e], &s, &c);
        sv[e] = (short)f2bf(s);
        cv[e] = (short)f2bf(c);
    }
    const int srow = (row >> 6) * 128 + (row & 63);
    *reinterpret_cast<bf16x8*>(sc + (size_t)srow * N_DIM + kk)        = sv;
    *reinterpret_cast<bf16x8*>(sc + (size_t)(srow + 64) * N_DIM + kk) = cv;
}

// 8-phase-template GEMM (m201 port): tile 256 sc-rows x 256 cols, BK=64,
// 512 thr / 8 waves (2M x 4N), wave out 128x64, acc[8][4] f32x4.
// K-tile = 4 phases (mi-half x k-half), each: {ds_read 8(+4 B at half start)
// pre-barrier, issue 1 staging unit U (4 gload_lds), barrier, 16 MFMA,
// [counted vmcnt], barrier}. Staging pipeline 3 U deep, vmcnt(8) steady.
__global__ __launch_bounds__(512, 1)
void k_gemm(const unsigned short* __restrict__ sc,
            const float* __restrict__ theta,
            const float* __restrict__ noise,
            const float* __restrict__ omega,
            const unsigned short* __restrict__ Kbf,
            float* __restrict__ out, int rbase) {
    // granule-major: [buf][g(8)][row(256)][8 bf16]; g = k/8 within BK=64.
    // kh0 = g 0..3, kh1 = g 4..7. 64 KB each, 128 KB total. 0 bank conflicts
    // measured on this layout (R4/R5).
    __shared__ unsigned short sA[2][8][256][8];
    __shared__ unsigned short sB[2][8][256][8];

    const int tid  = threadIdx.x;
    const int lane = tid & 63;
    const int w    = tid >> 6;      // 0..7
    const int wm   = w >> 2;        // 0..1 (128 sc rows)
    const int wn   = w & 3;         // 0..3 (64 cols)
    const int lr   = lane & 15;
    const int kq   = lane >> 4;

    const int nwg     = gridDim.x;          // multiple of 8
    const int cpx     = nwg >> 3;
    const int logical = (blockIdx.x & 7) * cpx + (blockIdx.x >> 3);
    const int mt      = logical >> 2;       // row panel (256 sc / 128 theta rows)
    const int nt      = logical & 3;        // col tile (256 cols)

    f32x4 acc[8][4];
#pragma unroll
    for (int mi = 0; mi < 8; ++mi)
#pragma unroll
        for (int ni = 0; ni < 4; ++ni)
            acc[mi][ni] = (f32x4){0.f, 0.f, 0.f, 0.f};

    // Staging unit U(u): u = 2T + kh; writes buf T&1, granules kh*4..+4 of
    // both A and B. 4 gload_lds per thread (FIFO unit for vmcnt accounting).
    auto stageU = [&](int u) {
        const int T = u >> 1, buf = T & 1, g0 = (u & 1) * 4;
#pragma unroll
        for (int i = 0; i < 2; ++i) {
            const int c  = w * 2 + i;       // 0..15
            const int g  = g0 + (c >> 2);
            const int rb = (c & 3) * 64;
            gload_lds16(sc  + (size_t)(mt * 256 + rb + lane) * N_DIM + T * 64 + g * 8,
                        &sA[buf][g][rb][0]);
            gload_lds16(Kbf + (size_t)(nt * 256 + rb + lane) * N_DIM + T * 64 + g * 8,
                        &sB[buf][g][rb][0]);
        }
    };

    // Prologue: 3 units in flight; guarantee U0 (kh0 of tile 0) landed.
    stageU(0); stageU(1); stageU(2);
    asm volatile("s_waitcnt vmcnt(8)" ::: "memory");
    __builtin_amdgcn_s_barrier();

    for (int t = 0; t < 16; ++t) {
        const int buf = t & 1;
        bf16x8 aF[4], bF[4];

        // ========== P1: kk=0, mi 0..3 (reads kh0: guaranteed by prev vm) =====
#pragma unroll
        for (int ni = 0; ni < 4; ++ni)
            bF[ni] = *reinterpret_cast<const bf16x8*>(&sB[buf][kq][wn * 64 + ni * 16 + lr][0]);
#pragma unroll
        for (int mi = 0; mi < 4; ++mi)
            aF[mi] = *reinterpret_cast<const bf16x8*>(&sA[buf][kq][wm * 128 + mi * 16 + lr][0]);
        if (t <= 14) stageU(2 * t + 3);     // kh1(t+1) -> buf^1 (readers done P4(t-1))
        __builtin_amdgcn_s_barrier();
        __builtin_amdgcn_s_setprio(1);
#pragma unroll
        for (int mi = 0; mi < 4; ++mi)
#pragma unroll
            for (int ni = 0; ni < 4; ++ni)
                acc[mi][ni] = __builtin_amdgcn_mfma_f32_16x16x32_bf16(aF[mi], bF[ni], acc[mi][ni], 0, 0, 0);
        __builtin_amdgcn_s_setprio(0);
        __builtin_amdgcn_s_barrier();

        // ========== P2: kk=0, mi 4..7 (bF reused) ==========
#pragma unroll
        for (int mi = 0; mi < 4; ++mi)
            aF[mi] = *reinterpret_cast<const bf16x8*>(&sA[buf][kq][wm * 128 + (mi + 4) * 16 + lr][0]);
        __builtin_amdgcn_s_barrier();
        __builtin_amdgcn_s_setprio(1);
#pragma unroll
        for (int mi = 0; mi < 4; ++mi)
#pragma unroll
            for (int ni = 0; ni < 4; ++ni)
                acc[mi + 4][ni] = __builtin_amdgcn_mfma_f32_16x16x32_bf16(aF[mi], bF[ni], acc[mi + 4][ni], 0, 0, 0);
        __builtin_amdgcn_s_setprio(0);
        // vm_b: guarantee kh1(t) = U(2t+1) landed before P3 reads it.
        if (t < 15) asm volatile("s_waitcnt vmcnt(8)" ::: "memory");
        else        asm volatile("s_waitcnt vmcnt(0)" ::: "memory");
        __builtin_amdgcn_s_barrier();

        // ========== P3: kk=1, mi 0..3 ==========
#pragma unroll
        for (int ni = 0; ni < 4; ++ni)
            bF[ni] = *reinterpret_cast<const bf16x8*>(&sB[buf][4 + kq][wn * 64 + ni * 16 + lr][0]);
#pragma unroll
        for (int mi = 0; mi < 4; ++mi)
            aF[mi] = *reinterpret_cast<const bf16x8*>(&sA[buf][4 + kq][wm * 128 + mi * 16 + lr][0]);
        if (t <= 13) stageU(2 * t + 4);     // kh0(t+2) -> same buf, kh0 region (readers done P2(t))
        __builtin_amdgcn_s_barrier();
        __builtin_amdgcn_s_setprio(1);
#pragma unroll
        for (int mi = 0; mi < 4; ++mi)
#pragma unroll
            for (int ni = 0; ni < 4; ++ni)
                acc[mi][ni] = __builtin_amdgcn_mfma_f32_16x16x32_bf16(aF[mi], bF[ni], acc[mi][ni], 0, 0, 0);
        __builtin_amdgcn_s_setprio(0);
        __builtin_amdgcn_s_barrier();

        // ========== P4: kk=1, mi 4..7 ==========
#pragma unroll
        for (int mi = 0; mi < 4; ++mi)
            aF[mi] = *reinterpret_cast<const bf16x8*>(&sA[buf][4 + kq][wm * 128 + (mi + 4) * 16 + lr][0]);
        __builtin_amdgcn_s_barrier();
        __builtin_amdgcn_s_setprio(1);
#pragma unroll
        for (int mi = 0; mi < 4; ++mi)
#pragma unroll
            for (int ni = 0; ni < 4; ++ni)
                acc[mi + 4][ni] = __builtin_amdgcn_mfma_f32_16x16x32_bf16(aF[mi], bF[ni], acc[mi + 4][ni], 0, 0, 0);
        __builtin_amdgcn_s_setprio(0);
        // vm_c: guarantee kh0(t+1) = U(2t+2) landed before next P1 reads it.
        if (t < 14)       asm volatile("s_waitcnt vmcnt(8)" ::: "memory");
        else if (t == 14) asm volatile("s_waitcnt vmcnt(4)" ::: "memory");
        __builtin_amdgcn_s_barrier();
    }

    // ---- epilogue: in-register. mi 0..3 = Ks, mi+4 = Kc, same theta rows ----
#pragma unroll
    for (int ni = 0; ni < 4; ++ni) {
        const int colg = nt * 256 + wn * 64 + ni * 16 + lr;
        const float om = omega[colg];
#pragma unroll
        for (int mi = 0; mi < 4; ++mi) {
#pragma unroll
            for (int v = 0; v < 4; ++v) {
                const int rowg = mt * 128 + wm * 64 + mi * 16 + (lane >> 4) * 4 + v;
                const size_t idx = (size_t)(rbase + rowg) * N_DIM + colg;
                const float th = theta[idx];
                float sn, cn;
                __sincosf(th, &sn, &cn);
                const float coup = cn * acc[mi][ni][v] - sn * acc[mi + 4][ni][v];
                out[idx] = th + (om + coup) * DT_C + noise[idx] * NS_SCALE;
            }
        }
    }
}

// ---------------- fallback (R2 kernel, ws too small) ----------------
#define FB_BM 64
#define FB_BN 256
__global__ __launch_bounds__(512, 4)
void k_fused_fb(const float* __restrict__ theta,
                const float* __restrict__ noise,
                const float* __restrict__ omega,
                const unsigned short* __restrict__ Kbf,
                float* __restrict__ out) {
    __shared__ unsigned short sA[2][2][4][FB_BM][8];
    __shared__ unsigned short sB[2][4][FB_BN][8];

    const int tid  = threadIdx.x;
    const int lane = tid & 63;
    const int w    = tid >> 6;
    const int wm   = w >> 2;
    const int wn   = w & 3;

    const int nwg     = gridDim.x;
    const int cpx     = nwg >> 3;
    const int logical = (blockIdx.x & 7) * cpx + (blockIdx.x >> 3);
    const int mt      = logical >> 2;
    const int nt      = logical & 3;
    const int row0    = mt * FB_BM;
    const int col0    = nt * FB_BN;

    const int q = tid >> 7;
    const int r = (tid >> 1) & 63;
    const int h = tid & 1;
    const int rb  = (w & 3) * 64;
    const int it0 = (w >> 2) * 2;

    f32x4 accS[2][4], accC[2][4];
#pragma unroll
    for (int mi = 0; mi < 2; ++mi)
#pragma unroll
        for (int ni = 0; ni < 4; ++ni) {
            accS[mi][ni] = (f32x4){0.f, 0.f, 0.f, 0.f};
            accC[mi][ni] = (f32x4){0.f, 0.f, 0.f, 0.f};
        }

    auto stage = [&](int buf, int kt) {
#pragma unroll
        for (int j = 0; j < 2; ++j) {
            const int it = it0 + j;
            const unsigned short* src =
                Kbf + (size_t)(col0 + rb + lane) * N_DIM + kt * 32 + it * 8;
            gload_lds16(src, &sB[buf][it][rb][0]);
        }
        const float* gp = theta + (size_t)(row0 + r) * N_DIM + kt * 32 + q * 8 + h * 4;
        float4 v = *reinterpret_cast<const float4*>(gp);
        ushort4 sv, cv;
        {
            float s0, c0, s1, c1, s2, c2, s3, c3;
            __sincosf(v.x, &s0, &c0);
            __sincosf(v.y, &s1, &c1);
            __sincosf(v.z, &s2, &c2);
            __sincosf(v.w, &s3, &c3);
            sv.x = f2bf(s0); sv.y = f2bf(s1); sv.z = f2bf(s2); sv.w = f2bf(s3);
            cv.x = f2bf(c0); cv.y = f2bf(c1); cv.z = f2bf(c2); cv.w = f2bf(c3);
        }
        *reinterpret_cast<ushort4*>(&sA[buf][0][q][r][h * 4]) = sv;
        *reinterpret_cast<ushort4*>(&sA[buf][1][q][r][h * 4]) = cv;
    };

    auto compute = [&](int buf) {
        const int kq2 = lane >> 4;
        const int lr2 = lane & 15;
        bf16x8 aS[2], aC[2];
#pragma unroll
        for (int mi = 0; mi < 2; ++mi) {
            aS[mi] = *reinterpret_cast<const bf16x8*>(&sA[buf][0][kq2][wm * 32 + mi * 16 + lr2][0]);
            aC[mi] = *reinterpret_cast<const bf16x8*>(&sA[buf][1][kq2][wm * 32 + mi * 16 + lr2][0]);
        }
#pragma unroll
        for (int ni = 0; ni < 4; ++ni) {
            bf16x8 bF = *reinterpret_cast<const bf16x8*>(&sB[buf][kq2][wn * 64 + ni * 16 + lr2][0]);
#pragma unroll
            for (int mi = 0; mi < 2; ++mi) {
                accS[mi][ni] = __builtin_amdgcn_mfma_f32_16x16x32_bf16(aS[mi], bF, accS[mi][ni], 0, 0, 0);
                accC[mi][ni] = __builtin_amdgcn_mfma_f32_16x16x32_bf16(aC[mi], bF, accC[mi][ni], 0, 0, 0);
            }
        }
    };

    stage(0, 0);
    __syncthreads();
    int cur = 0;
    for (int kt = 0; kt < 32; ++kt) {
        if (kt + 1 < 32) stage(cur ^ 1, kt + 1);
        compute(cur);
        __syncthreads();
        cur ^= 1;
    }

#pragma unroll
    for (int mi = 0; mi < 2; ++mi) {
#pragma unroll
        for (int ni = 0; ni < 4; ++ni) {
            const int colg = col0 + wn * 64 + ni * 16 + (lane & 15);
            const float om = omega[colg];
#pragma unroll
            for (int v = 0; v < 4; ++v) {
                const int rowg = row0 + wm * 32 + mi * 16 + (lane >> 4) * 4 + v;
                const size_t idx = (size_t)rowg * N_DIM + colg;
                const float th = theta[idx];
                float sn, cn;
                __sincosf(th, &sn, &cn);
                const float coup = cn * accS[mi][ni][v] - sn * accC[mi][ni][v];
                out[idx] = th + (om + coup) * DT_C + noise[idx] * NS_SCALE;
            }
        }
    }
}

extern "C" void kernel_launch(void* const* d_in, const int* in_sizes, int n_in,
                              void* d_out, int out_size, void* d_ws, size_t ws_size,
                              hipStream_t stream) {
    const float* theta = (const float*)d_in[0];
    const float* noise = (const float*)d_in[1];
    const float* omega = (const float*)d_in[2];
    const float* K     = (const float*)d_in[3];
    float* out = (float*)d_out;

    unsigned short* Kbf = (unsigned short*)d_ws;   // 2 MB @ offset 0
    k_convK<<<(N_DIM * N_DIM) / (256 * 4), 256, 0, stream>>>(K, Kbf);

    // Chunk R rows: sc chunk needs R*4096 bytes after a 4MB reserve.
    size_t avail = ws_size > (size_t)(4 << 20) ? ws_size - (size_t)(4 << 20) : 0;
    int R = 0;
    for (int cand = 65536; cand >= 1024; cand >>= 1)
        if ((size_t)cand * 4096 <= avail) { R = cand; break; }

    if (R > 0) {
        unsigned short* sc = (unsigned short*)((char*)d_ws + (4 << 20));
        const int nch = B_DIM / R;
        for (int ch = 0; ch < nch; ++ch) {
            const int rbase = ch * R;
            k_prep<<<R / 2, 256, 0, stream>>>(theta, sc, rbase);
            k_gemm<<<(R / 128) * 4, 512, 0, stream>>>(sc, theta, noise, omega, Kbf, out, rbase);
        }
    } else {
        k_fused_fb<<<(B_DIM / FB_BM) * (N_DIM / FB_BN), 512, 0, stream>>>(
            theta, noise, omega, Kbf, out);
    }
}